// Round 12
// baseline (330.886 us; speedup 1.0000x reference)
//
#include <hip/hip_runtime.h>
#include <stdint.h>

// ---- problem dims ----
#define NB   32
#define CIN  128
#define COUT 256
#define HH   56
#define WW   56
#define S1   (HH*WW)      // 3136
#define HO   28
#define WO   28
#define S2   (HO*WO)      // 784
#define NS1  (NB*S1)      // 100352
#define NS2  (NB*S2)      // 25088
#define TOT2 (NS2*COUT)   // 6422528
#define EPSV 1e-5f

// ---- workspace layout (bytes) ----
constexpr size_t OFF_XBITS = 0;                                 // NS1*8*4 = 3,211,264
constexpr size_t OFF_WB1   = OFF_XBITS + (size_t)NS1*8*4;       // 8 KB
constexpr size_t OFF_WB3   = OFF_WB1 + 256*8*4;                 // 16 KB
constexpr size_t OFF_WDW   = OFF_WB3 + 256*16*4;                // 4 KB
constexpr size_t OFF_ACC   = OFF_WDW + 4096;                    // 12 KB
constexpr size_t OFF_WBADJ = OFF_ACC + 3*256*4*sizeof(int);     // 256*128*2 = 65,536
constexpr size_t OFF_XG    = OFF_WBADJ + (size_t)COUT*CIN*2;    // NS2*128*2 = 6,422,528
constexpr size_t OFF_OUT1  = OFF_XG + (size_t)NS2*CIN*2;        // NS1*COUT i8 = 25,690,112
constexpr size_t OFF_OUT2  = OFF_OUT1 + (size_t)NS1*COUT;       // i8 6,422,528
constexpr size_t OFF_XB2   = OFF_OUT2 + (size_t)TOT2;           // NS2*16*4 = 1,605,632
constexpr size_t OFF_OUT3  = OFF_XB2 + (size_t)NS2*16*4;        // i16 12,845,056
// total ~56 MB

typedef __attribute__((ext_vector_type(8))) short bf16x8;
typedef __attribute__((ext_vector_type(4))) float f32x4;

__device__ __forceinline__ uint32_t f2bf(float v) {
  uint32_t u = __float_as_uint(v);
  return (u + 0x7fffu + ((u >> 16) & 1u)) >> 16;   // RNE bf16 bits
}

// finalize BN scale/shift from exact integer sums of prelu output
__device__ __forceinline__ void bn_finalize(const int* __restrict__ acc4,
                                            float a, float g, float b, float inv_ns,
                                            float& sc, float& sh) {
  float ps = (float)acc4[0];   // sum of v where v>0
  float ng = (float)acc4[1];   // sum of v where v<0
  float pq = (float)acc4[2];   // sum of v^2 where v>0
  float nq = (float)acc4[3];   // sum of v^2 where v<0
  float mean = (ps + a*ng) * inv_ns;
  float ex2  = (pq + a*a*nq) * inv_ns;
  float var  = ex2 - mean*mean;
  float rs   = rsqrtf(var + EPSV);
  sc = rs * g;
  sh = b - mean * sc;
}

// ---------------- pack x into bitplanes + bf16 stride-2 tile, fused weight pack ----------------
__global__ __launch_bounds__(256) void packx_kernel(
    const float* __restrict__ x, uint32_t* __restrict__ xbits,
    uint32_t* __restrict__ xg,
    const float* __restrict__ w1, const float* __restrict__ w3,
    const float* __restrict__ wdw, const float* __restrict__ wadj,
    uint32_t* __restrict__ wb1, uint32_t* __restrict__ wb3,
    int8_t* __restrict__ wdws, uint32_t* __restrict__ wbadj,
    int* __restrict__ accbase) {
  int wdx = blockIdx.y;                     // 0..3
  // fused weight pack + acc zero: wave 0 of blocks (bx<256, wdx==0)
  if (wdx == 0 && blockIdx.x < 256 && threadIdx.x < 64) {
    int co = blockIdx.x;
    int l  = threadIdx.x;
    if (l < 12) {
      int set = l >> 2, k = l & 3;
      accbase[set*1024 + co*4 + k] = 0;
    }
    for (int h = 0; h < 2; ++h) {
      float v = w1[(size_t)co*CIN + h*64 + l];
      unsigned long long bp = __ballot(v > 0.f);
      unsigned long long bn = __ballot(v < 0.f);
      if (l == 0) {
        wb1[co*8 + 2*h    ] = (uint32_t)bp;
        wb1[co*8 + 2*h + 1] = (uint32_t)(bp >> 32);
        wb1[co*8 + 4 + 2*h    ] = (uint32_t)bn;
        wb1[co*8 + 4 + 2*h + 1] = (uint32_t)(bn >> 32);
      }
    }
    for (int h = 0; h < 4; ++h) {
      float v = w3[(size_t)co*COUT + h*64 + l];
      unsigned long long bp = __ballot(v > 0.f);
      unsigned long long bn = __ballot(v < 0.f);
      if (l == 0) {
        wb3[co*16 + 2*h    ] = (uint32_t)bp;
        wb3[co*16 + 2*h + 1] = (uint32_t)(bp >> 32);
        wb3[co*16 + 8 + 2*h    ] = (uint32_t)bn;
        wb3[co*16 + 8 + 2*h + 1] = (uint32_t)(bn >> 32);
      }
    }
    if (l < 9) {
      float v = wdw[co*9 + l];
      wdws[co*9 + l] = (int8_t)((v > 0.f) - (v < 0.f));
    }
    {
      float v0 = wadj[(size_t)co*CIN + 2*l];
      float v1 = wadj[(size_t)co*CIN + 2*l + 1];
      wbadj[co*64 + l] = f2bf(v0) | (f2bf(v1) << 16);
    }
  }

  int m = blockIdx.x*256 + threadIdx.x;     // m = n*S1 + hw
  int n = m / S1, hw = m % S1;
  size_t base = ((size_t)n*CIN + wdx*32)*S1 + hw;
  uint32_t p = 0, q = 0;
  uint32_t bv[16];
  #pragma unroll
  for (int j = 0; j < 32; ++j) {
    float v = x[base + (size_t)j*S1];
    p |= (uint32_t)(v > 0.f) << j;
    q |= (uint32_t)(v < 0.f) << j;
    uint32_t b = f2bf(v);
    if (j & 1) bv[j >> 1] |= b << 16; else bv[j >> 1] = b;
  }
  xbits[(size_t)m*8 + wdx    ] = p;
  xbits[(size_t)m*8 + 4 + wdx] = q;
  int h = hw / WW, w = hw % WW;
  if (((h | w) & 1) == 0) {
    int m2 = n*S2 + (h >> 1)*WO + (w >> 1);
    uint4* dst = (uint4*)(xg + (size_t)m2*64 + wdx*16);
    dst[0] = make_uint4(bv[0],  bv[1],  bv[2],  bv[3]);
    dst[1] = make_uint4(bv[4],  bv[5],  bv[6],  bv[7]);
    dst[2] = make_uint4(bv[8],  bv[9],  bv[10], bv[11]);
    dst[3] = make_uint4(bv[12], bv[13], bv[14], bv[15]);
  }
}

// ---------------- conv1: binary 1x1 XOR popcount + FUSED per-channel stats ----------------
__global__ __launch_bounds__(256) void conv1_kernel(
    const uint32_t* __restrict__ xb, const uint32_t* __restrict__ wb,
    int8_t* __restrict__ out1, int* __restrict__ accum1) {
  int tid = threadIdx.x;
  int m = blockIdx.x*256 + tid;
  int n = m / S1, hw = m % S1;
  const uint32_t* xw = xb + (size_t)m*8;
  uint32_t p0 = xw[0], p1 = xw[1], p2 = xw[2], p3 = xw[3];
  uint32_t q0 = xw[4], q1 = xw[5], q2 = xw[6], q3 = xw[7];
  int co0 = blockIdx.y * 32;
  size_t obase = ((size_t)n*COUT)*S1 + hw;
  int8_t a8[32];
  bool nozero = (((p0|q0) & (p1|q1) & (p2|q2) & (p3|q3)) == 0xffffffffu);
  if (nozero) {
    #pragma unroll 4
    for (int j = 0; j < 32; ++j) {
      const uint32_t* w8 = wb + (size_t)(co0 + j)*8;
      int s = __popc(p0 ^ w8[0]) + __popc(p1 ^ w8[1])
            + __popc(p2 ^ w8[2]) + __popc(p3 ^ w8[3]);
      int acc = 128 - 2*s;
      if (acc > 127) acc = 127;
      a8[j] = (int8_t)acc;
    }
  } else {
    #pragma unroll 4
    for (int j = 0; j < 32; ++j) {
      const uint32_t* w8 = wb + (size_t)(co0 + j)*8;
      uint32_t a0 = w8[0], a1 = w8[1], a2 = w8[2], a3 = w8[3];
      uint32_t b0 = w8[4], b1 = w8[5], b2 = w8[6], b3 = w8[7];
      int acc = __popc(p0&a0) + __popc(p1&a1) + __popc(p2&a2) + __popc(p3&a3)
              + __popc(q0&b0) + __popc(q1&b1) + __popc(q2&b2) + __popc(q3&b3)
              - __popc(p0&b0) - __popc(p1&b1) - __popc(p2&b2) - __popc(p3&b3)
              - __popc(q0&a0) - __popc(q1&a1) - __popc(q2&a2) - __popc(q3&a3);
      if (acc > 127) acc = 127;
      a8[j] = (int8_t)acc;
    }
  }
  // global store
  #pragma unroll 8
  for (int j = 0; j < 32; ++j) out1[obase + (size_t)(co0 + j)*S1] = a8[j];

  // fused stats. Write: row stride 36B = 9 dwords (odd -> 2-way max).
  __shared__ int8_t vals[256][36];
  #pragma unroll
  for (int k = 0; k < 8; ++k) {
    uint32_t w4 = (uint32_t)(uint8_t)a8[4*k]
                | ((uint32_t)(uint8_t)a8[4*k+1] << 8)
                | ((uint32_t)(uint8_t)a8[4*k+2] << 16)
                | ((uint32_t)(uint8_t)a8[4*k+3] << 24);
    *(uint32_t*)&vals[tid][4*k] = w4;
  }
  __syncthreads();
  int j = tid >> 3;     // channel 0..31 (8 per wave)
  int c = tid & 7;      // chunk 0..7
  int ps = 0, ns = 0, pq = 0, nq = 0;
  // INTERLEAVED row walk: rows c, c+8, ..., c+248.  Bank = (9c + j/4) mod 32:
  // 9c distinct for c=0..7 -> <=2-way (free).  (c*32+i was 32-way: c*288 dwords = 0 mod 32.)
  #pragma unroll
  for (int i = 0; i < 32; ++i) {
    int v = (int)vals[c + 8*i][j];
    if (v > 0) { ps += v; pq += v*v; } else { ns += v; nq += v*v; }
  }
  #pragma unroll
  for (int off = 4; off; off >>= 1) {
    ps += __shfl_xor(ps, off);
    ns += __shfl_xor(ns, off);
    pq += __shfl_xor(pq, off);
    nq += __shfl_xor(nq, off);
  }
  if (c == 0) {
    atomicAdd(&accum1[(co0 + j)*4 + 0], ps);
    atomicAdd(&accum1[(co0 + j)*4 + 1], ns);
    atomicAdd(&accum1[(co0 + j)*4 + 2], pq);
    atomicAdd(&accum1[(co0 + j)*4 + 3], nq);
  }
}

// ---------------- depthwise 3x3 s2 p1: LDS signs, inline thr1, fused stats2 ----------------
#define DW_SLABS 8
#define DW_RB    68
__global__ __launch_bounds__(256) void dw_kernel(
    const int8_t* __restrict__ out1, const int8_t* __restrict__ wdws,
    const int* __restrict__ acc1, const float* __restrict__ a1,
    const float* __restrict__ g1, const float* __restrict__ b1,
    int8_t* __restrict__ out2, int* __restrict__ accum2) {
  __shared__ int8_t sl[DW_SLABS][57][DW_RB];   // 30,464 B
  __shared__ int sTp[DW_SLABS], sTn[DW_SLABS], sAcc[DW_SLABS][4];
  int tid = threadIdx.x;
  int nc0 = blockIdx.x * DW_SLABS;
  int co0 = nc0 & (COUT-1);                    // 256 % 8 == 0: no wrap within block

  int* slw = (int*)&sl[0][0][0];
  #pragma unroll
  for (int i = tid; i < DW_SLABS*57*DW_RB/4; i += 256) slw[i] = 0;
  if (tid < DW_SLABS) { sTp[tid] = 128; sTn[tid] = -129; }
  if (tid < DW_SLABS*4) sAcc[tid >> 2][tid & 3] = 0;
  __syncthreads();

  // inline thresholds (32 threads per slab, 8 candidate v each)
  {
    int slab = tid >> 5;
    int co = co0 + slab;
    float av = a1[co], sc, sh;
    bn_finalize(acc1 + co*4, av, g1[co], b1[co], 1.f/NS1, sc, sh);
    int tp = 128, tn = -129;
    int v0 = -128 + (tid & 31)*8;
    #pragma unroll
    for (int k = 0; k < 8; ++k) {
      int v = v0 + k;
      float f = (float)v;
      float pr = f > 0.f ? f : av*f;
      float tv = pr*sc + sh;
      if (tv > 0.f && v < tp) tp = v;
      if (tv < 0.f && v > tn) tn = v;
    }
    atomicMin(&sTp[slab], tp);
    atomicMax(&sTn[slab], tn);
  }
  __syncthreads();

  // stage signs
  for (int i = tid; i < DW_SLABS*784; i += 256) {
    int slab = i / 784;
    int d    = i - slab*784;
    int ih   = d / 14;
    int iwd  = d - ih*14;
    int Tp = sTp[slab], Tn = sTn[slab];
    uint32_t v4 = ((const uint32_t*)(out1 + (size_t)(nc0 + slab)*S1))[d];
    uint32_t s4 = 0;
    #pragma unroll
    for (int k = 0; k < 4; ++k) {
      int v = (int)(int8_t)(v4 >> (8*k));
      int s = (v >= Tp) - (v <= Tn);
      s4 |= (uint32_t)(s & 0xff) << (8*k);
    }
    *(uint32_t*)&sl[slab][ih + 1][4 + 4*iwd] = s4;
  }
  __syncthreads();

  // compute one output row per thread (slab, ho) + local stats
  int psum = 0, nsum = 0, psq = 0, nsq = 0;
  int slabD = tid / HO;
  if (tid < DW_SLABS*HO) {
    int ho   = tid - slabD*HO;
    int nc = nc0 + slabD;
    int co = co0 + slabD;
    int wv[9];
    #pragma unroll
    for (int k = 0; k < 9; ++k) wv[k] = wdws[co*9 + k];
    const uint32_t* r0 = (const uint32_t*)&sl[slabD][2*ho    ][4];
    const uint32_t* r1 = (const uint32_t*)&sl[slabD][2*ho + 1][4];
    const uint32_t* r2 = (const uint32_t*)&sl[slabD][2*ho + 2][4];
    uint32_t* o32 = (uint32_t*)(out2 + (size_t)nc*S2 + ho*WO);
    int c0 = 0, c1 = 0, c2 = 0;
    uint32_t obuf = 0;
    #pragma unroll
    for (int q = 0; q < 14; ++q) {
      uint32_t d0 = r0[q], d1 = r1[q], d2 = r2[q];
      int s00=(int)(int8_t)d0, s01=(int)(int8_t)(d0>>8), s02=(int)(int8_t)(d0>>16), s03=(int)(int8_t)(d0>>24);
      int s10=(int)(int8_t)d1, s11=(int)(int8_t)(d1>>8), s12=(int)(int8_t)(d1>>16), s13=(int)(int8_t)(d1>>24);
      int s20=(int)(int8_t)d2, s21=(int)(int8_t)(d2>>8), s22=(int)(int8_t)(d2>>16), s23=(int)(int8_t)(d2>>24);
      int a0 = c0*wv[0] + s00*wv[1] + s01*wv[2]
             + c1*wv[3] + s10*wv[4] + s11*wv[5]
             + c2*wv[6] + s20*wv[7] + s21*wv[8];
      int a1v = s01*wv[0] + s02*wv[1] + s03*wv[2]
              + s11*wv[3] + s12*wv[4] + s13*wv[5]
              + s21*wv[6] + s22*wv[7] + s23*wv[8];
      c0 = s03; c1 = s13; c2 = s23;
      if (a0 > 0) { psum += a0; psq += a0*a0; } else { nsum += a0; nsq += a0*a0; }
      if (a1v > 0) { psum += a1v; psq += a1v*a1v; } else { nsum += a1v; nsq += a1v*a1v; }
      if ((q & 1) == 0) {
        obuf = (uint32_t)(a0 & 0xff) | ((uint32_t)(a1v & 0xff) << 8);
      } else {
        obuf |= ((uint32_t)(a0 & 0xff) << 16) | ((uint32_t)(a1v & 0xff) << 24);
        o32[q >> 1] = obuf;
      }
    }
    atomicAdd(&sAcc[slabD][0], psum);
    atomicAdd(&sAcc[slabD][1], nsum);
    atomicAdd(&sAcc[slabD][2], psq);
    atomicAdd(&sAcc[slabD][3], nsq);
  }
  __syncthreads();

  if (tid < DW_SLABS*4) {
    int slab = tid >> 2, k = tid & 3;
    atomicAdd(&accum2[(co0 + slab)*4 + k], sAcc[slab][k]);
  }
}

// ---------------- pack sign(BN2(prelu(out2))): inline thr2 + thresholds ----------------
__global__ __launch_bounds__(256) void pack2_kernel(
    const int8_t* __restrict__ out2, const int* __restrict__ acc2,
    const float* __restrict__ a2, const float* __restrict__ g2,
    const float* __restrict__ b2, uint32_t* __restrict__ xb2) {
  __shared__ int sTp[32], sTn[32];
  int wdx = blockIdx.y;                   // 0..7
  if (threadIdx.x < 32) {
    int c = wdx*32 + threadIdx.x;
    float av = a2[c], sc, sh;
    bn_finalize(acc2 + c*4, av, g2[c], b2[c], 1.f/NS2, sc, sh);
    int tp = 10, tn = -10;
    for (int v = -9; v <= 9; ++v) {
      float f = (float)v;
      float pr = f > 0.f ? f : av*f;
      float tv = pr*sc + sh;
      if (tv > 0.f && v < tp) tp = v;
      if (tv < 0.f && v > tn) tn = v;
    }
    sTp[threadIdx.x] = tp; sTn[threadIdx.x] = tn;
  }
  __syncthreads();
  int m = blockIdx.x*256 + threadIdx.x;   // n*S2 + hw
  int n = m / S2, hw = m % S2;
  uint32_t p = 0, q = 0;
  #pragma unroll
  for (int j = 0; j < 32; ++j) {
    int c = wdx*32 + j;
    int v = out2[(size_t)(n*COUT + c)*S2 + hw];
    p |= (uint32_t)(v >= sTp[j]) << j;
    q |= (uint32_t)(v <= sTn[j]) << j;
  }
  xb2[(size_t)m*16 + wdx    ] = p;
  xb2[(size_t)m*16 + 8 + wdx] = q;
}

// ---------------- conv3: binary 1x1 XOR fast path + FUSED per-channel stats ----------------
__global__ __launch_bounds__(256) void conv3_kernel(
    const uint32_t* __restrict__ xb2, const uint32_t* __restrict__ wb3,
    int16_t* __restrict__ out3, int* __restrict__ accum3) {
  int tid = threadIdx.x;
  int m = blockIdx.x*256 + tid;   // NS2
  int n = m / S2, hw = m % S2;
  const uint32_t* xw = xb2 + (size_t)m*16;
  uint32_t P[8], Q[8];
  #pragma unroll
  for (int i = 0; i < 8; ++i) { P[i] = xw[i]; Q[i] = xw[8+i]; }
  int co0 = blockIdx.y * 32;
  size_t obase = ((size_t)n*COUT)*S2 + hw;
  int16_t a16[32];
  uint32_t allm = 0xffffffffu;
  #pragma unroll
  for (int i = 0; i < 8; ++i) allm &= (P[i] | Q[i]);
  if (allm == 0xffffffffu) {
    #pragma unroll 2
    for (int j = 0; j < 32; ++j) {
      const uint32_t* w = wb3 + (size_t)(co0 + j)*16;
      int s = 0;
      #pragma unroll
      for (int i = 0; i < 8; ++i) s += __popc(P[i] ^ w[i]);
      a16[j] = (int16_t)(256 - 2*s);
    }
  } else {
    #pragma unroll 2
    for (int j = 0; j < 32; ++j) {
      const uint32_t* w = wb3 + (size_t)(co0 + j)*16;
      int acc = 0;
      #pragma unroll
      for (int i = 0; i < 8; ++i) {
        uint32_t wp = w[i], wn = w[8+i];
        acc += __popc(P[i]&wp) + __popc(Q[i]&wn) - __popc(P[i]&wn) - __popc(Q[i]&wp);
      }
      a16[j] = (int16_t)acc;
    }
  }
  #pragma unroll 8
  for (int j = 0; j < 32; ++j) out3[obase + (size_t)(co0 + j)*S2] = a16[j];

  // fused stats. Write: row stride 68B = 17 dwords (odd -> 2-way max).
  __shared__ int16_t vals[256][34];
  #pragma unroll
  for (int k = 0; k < 16; ++k) {
    uint32_t w2 = (uint32_t)(uint16_t)a16[2*k] | ((uint32_t)(uint16_t)a16[2*k+1] << 16);
    *(uint32_t*)&vals[tid][2*k] = w2;
  }
  __syncthreads();
  int j = tid >> 3;     // channel 0..31
  int c = tid & 7;      // chunk
  int ps = 0, ns = 0, pq = 0, nq = 0;
  // INTERLEAVED row walk (rows c+8i): bank = (17c + j/2) mod 32, 17c distinct -> <=4-way.
  #pragma unroll
  for (int i = 0; i < 32; ++i) {
    int v = (int)vals[c + 8*i][j];
    if (v > 0) { ps += v; pq += v*v; } else { ns += v; nq += v*v; }
  }
  #pragma unroll
  for (int off = 4; off; off >>= 1) {
    ps += __shfl_xor(ps, off);
    ns += __shfl_xor(ns, off);
    pq += __shfl_xor(pq, off);
    nq += __shfl_xor(nq, off);
  }
  if (c == 0) {
    atomicAdd(&accum3[(co0 + j)*4 + 0], ps);
    atomicAdd(&accum3[(co0 + j)*4 + 1], ns);
    atomicAdd(&accum3[(co0 + j)*4 + 2], pq);
    atomicAdd(&accum3[(co0 + j)*4 + 3], nq);
  }
}

// ---------------- fused residual (bf16 MFMA, all 256 co per wave) + BN3 + add ----------------
// block 256 = 4 waves; wave: 16 m x 256 co; grid NS2/64. xg read exactly once.
__global__ __launch_bounds__(256) void resfinal_kernel(
    const uint16_t* __restrict__ xg, const uint16_t* __restrict__ wb,
    const int16_t* __restrict__ out3,
    const float* __restrict__ a3, const float* __restrict__ g3,
    const float* __restrict__ b3, const int* __restrict__ acc3,
    float* __restrict__ out) {
  int lane = threadIdx.x & 63;
  int wid  = threadIdx.x >> 6;
  int m0  = blockIdx.x*64 + wid*16;
  int r16 = lane & 15, hi = lane >> 4;
  int koff = hi * 8;

  const bf16x8* arow = (const bf16x8*)(xg + (size_t)(m0 + r16)*CIN + koff);
  bf16x8 af0 = arow[0], af1 = arow[4], af2 = arow[8], af3 = arow[12];

  f32x4 dd[16];
  #pragma unroll
  for (int t = 0; t < 16; ++t) {
    const bf16x8* brow = (const bf16x8*)(wb + (size_t)(t*16 + r16)*CIN + koff);
    f32x4 a = {0.f,0.f,0.f,0.f};
    a = __builtin_amdgcn_mfma_f32_16x16x32_bf16(af0, brow[0],  a, 0,0,0);
    a = __builtin_amdgcn_mfma_f32_16x16x32_bf16(af1, brow[4],  a, 0,0,0);
    a = __builtin_amdgcn_mfma_f32_16x16x32_bf16(af2, brow[8],  a, 0,0,0);
    a = __builtin_amdgcn_mfma_f32_16x16x32_bf16(af3, brow[12], a, 0,0,0);
    dd[t] = a;
  }

  int mrow = m0 + hi*4;
  int n  = mrow / S2;               // 16-m tiles never straddle n (784 % 16 == 0)
  int hw = mrow - n*S2;
  #pragma unroll
  for (int t = 0; t < 16; ++t) {
    int co = t*16 + r16;
    float av = a3[co], sc, sh;
    bn_finalize(acc3 + co*4, av, g3[co], b3[co], 1.f/NS2, sc, sh);
    size_t o = ((size_t)n*COUT + co)*S2 + hw;
    #pragma unroll
    for (int r = 0; r < 4; ++r) {
      float f = (float)out3[o + r];
      float pp = f > 0.f ? f : av*f;
      out[o + r] = pp*sc + sh + dd[t][r];
    }
  }
}

extern "C" void kernel_launch(void* const* d_in, const int* in_sizes, int n_in,
                              void* d_out, int out_size, void* d_ws, size_t ws_size,
                              hipStream_t stream) {
  (void)in_sizes; (void)n_in; (void)out_size; (void)ws_size;
  const float* x    = (const float*)d_in[0];
  const float* w1   = (const float*)d_in[1];
  const float* a1   = (const float*)d_in[2];
  const float* g1   = (const float*)d_in[3];
  const float* b1   = (const float*)d_in[4];
  const float* wdw  = (const float*)d_in[5];
  const float* a2   = (const float*)d_in[6];
  const float* g2   = (const float*)d_in[7];
  const float* b2   = (const float*)d_in[8];
  const float* w3   = (const float*)d_in[9];
  const float* a3   = (const float*)d_in[10];
  const float* g3   = (const float*)d_in[11];
  const float* b3   = (const float*)d_in[12];
  const float* wadj = (const float*)d_in[13];
  float* out = (float*)d_out;

  char* ws = (char*)d_ws;
  uint32_t* xbits = (uint32_t*)(ws + OFF_XBITS);
  uint32_t* wb1   = (uint32_t*)(ws + OFF_WB1);
  uint32_t* wb3   = (uint32_t*)(ws + OFF_WB3);
  int8_t*   wdws  = (int8_t*)  (ws + OFF_WDW);
  int*      acc1  = (int*)     (ws + OFF_ACC);
  int*      acc2  = acc1 + 256*4;
  int*      acc3  = acc2 + 256*4;
  uint32_t* wbadj = (uint32_t*)(ws + OFF_WBADJ);
  uint32_t* xg    = (uint32_t*)(ws + OFF_XG);
  int8_t*   out1  = (int8_t*)  (ws + OFF_OUT1);
  int8_t*   out2  = (int8_t*)  (ws + OFF_OUT2);
  uint32_t* xb2   = (uint32_t*)(ws + OFF_XB2);
  int16_t*  out3  = (int16_t*) (ws + OFF_OUT3);

  packx_kernel<<<dim3(NS1/256, 4), 256, 0, stream>>>(
      x, xbits, xg, w1, w3, wdw, wadj, wb1, wb3, wdws, wbadj, acc1);
  conv1_kernel<<<dim3(NS1/256, 8), 256, 0, stream>>>(xbits, wb1, out1, acc1);
  dw_kernel<<<NB*COUT/DW_SLABS, 256, 0, stream>>>(out1, wdws, acc1, a1, g1, b1, out2, acc2);
  pack2_kernel<<<dim3(NS2/256, 8), 256, 0, stream>>>(out2, acc2, a2, g2, b2, xb2);
  conv3_kernel<<<dim3(NS2/256, 8), 256, 0, stream>>>(xb2, wb3, out3, acc3);
  resfinal_kernel<<<NS2/64, 256, 0, stream>>>(
      (const uint16_t*)xg, (const uint16_t*)wbadj, out3, a3, g3, b3, acc3, out);
}

// Round 13
// 157.933 us; speedup vs baseline: 2.0951x; 2.0951x over previous
//
#include <hip/hip_runtime.h>
#include <stdint.h>

// ---- problem dims ----
#define NB   32
#define CIN  128
#define COUT 256
#define HH   56
#define WW   56
#define S1   (HH*WW)      // 3136
#define HO   28
#define WO   28
#define S2   (HO*WO)      // 784
#define NS1  (NB*S1)      // 100352
#define NS2  (NB*S2)      // 25088
#define TOT2 (NS2*COUT)   // 6422528
#define EPSV 1e-5f

// ---- workspace layout (bytes) ----
constexpr size_t OFF_XBITS = 0;                                 // NS1*8*4 = 3,211,264
constexpr size_t OFF_WB1   = OFF_XBITS + (size_t)NS1*8*4;       // 8 KB
constexpr size_t OFF_WB3   = OFF_WB1 + 256*8*4;                 // 16 KB
constexpr size_t OFF_WDW   = OFF_WB3 + 256*16*4;                // 4 KB
constexpr size_t OFF_ACC   = OFF_WDW + 4096;                    // 12 KB
constexpr size_t OFF_WBADJ = OFF_ACC + 3*256*4*sizeof(int);     // 256*128*2 = 65,536
constexpr size_t OFF_XG    = OFF_WBADJ + (size_t)COUT*CIN*2;    // NS2*128*2 = 6,422,528
constexpr size_t OFF_OUT1  = OFF_XG + (size_t)NS2*CIN*2;        // NS1*COUT i8 = 25,690,112
constexpr size_t OFF_OUT2  = OFF_OUT1 + (size_t)NS1*COUT;       // i8 6,422,528
constexpr size_t OFF_XB2   = OFF_OUT2 + (size_t)TOT2;           // NS2*16*4 = 1,605,632
constexpr size_t OFF_OUT3  = OFF_XB2 + (size_t)NS2*16*4;        // i16 12,845,056
// total ~56 MB

typedef __attribute__((ext_vector_type(8))) short bf16x8;
typedef __attribute__((ext_vector_type(4))) float f32x4;

__device__ __forceinline__ uint32_t f2bf(float v) {
  uint32_t u = __float_as_uint(v);
  return (u + 0x7fffu + ((u >> 16) & 1u)) >> 16;   // RNE bf16 bits
}

// finalize BN scale/shift from exact integer sums of prelu output
__device__ __forceinline__ void bn_finalize(const int* __restrict__ acc4,
                                            float a, float g, float b, float inv_ns,
                                            float& sc, float& sh) {
  float ps = (float)acc4[0];   // sum of v where v>0
  float ng = (float)acc4[1];   // sum of v where v<0
  float pq = (float)acc4[2];   // sum of v^2 where v>0
  float nq = (float)acc4[3];   // sum of v^2 where v<0
  float mean = (ps + a*ng) * inv_ns;
  float ex2  = (pq + a*a*nq) * inv_ns;
  float var  = ex2 - mean*mean;
  float rs   = rsqrtf(var + EPSV);
  sc = rs * g;
  sh = b - mean * sc;
}

// ---------------- pack x into bitplanes + bf16 stride-2 tile, fused weight pack ----------------
__global__ __launch_bounds__(256) void packx_kernel(
    const float* __restrict__ x, uint32_t* __restrict__ xbits,
    uint32_t* __restrict__ xg,
    const float* __restrict__ w1, const float* __restrict__ w3,
    const float* __restrict__ wdw, const float* __restrict__ wadj,
    uint32_t* __restrict__ wb1, uint32_t* __restrict__ wb3,
    int8_t* __restrict__ wdws, uint32_t* __restrict__ wbadj,
    int* __restrict__ accbase) {
  int wdx = blockIdx.y;                     // 0..3
  // fused weight pack + acc zero: wave 0 of blocks (bx<256, wdx==0)
  if (wdx == 0 && blockIdx.x < 256 && threadIdx.x < 64) {
    int co = blockIdx.x;
    int l  = threadIdx.x;
    if (l < 12) {
      int set = l >> 2, k = l & 3;
      accbase[set*1024 + co*4 + k] = 0;
    }
    for (int h = 0; h < 2; ++h) {
      float v = w1[(size_t)co*CIN + h*64 + l];
      unsigned long long bp = __ballot(v > 0.f);
      unsigned long long bn = __ballot(v < 0.f);
      if (l == 0) {
        wb1[co*8 + 2*h    ] = (uint32_t)bp;
        wb1[co*8 + 2*h + 1] = (uint32_t)(bp >> 32);
        wb1[co*8 + 4 + 2*h    ] = (uint32_t)bn;
        wb1[co*8 + 4 + 2*h + 1] = (uint32_t)(bn >> 32);
      }
    }
    for (int h = 0; h < 4; ++h) {
      float v = w3[(size_t)co*COUT + h*64 + l];
      unsigned long long bp = __ballot(v > 0.f);
      unsigned long long bn = __ballot(v < 0.f);
      if (l == 0) {
        wb3[co*16 + 2*h    ] = (uint32_t)bp;
        wb3[co*16 + 2*h + 1] = (uint32_t)(bp >> 32);
        wb3[co*16 + 8 + 2*h    ] = (uint32_t)bn;
        wb3[co*16 + 8 + 2*h + 1] = (uint32_t)(bn >> 32);
      }
    }
    if (l < 9) {
      float v = wdw[co*9 + l];
      wdws[co*9 + l] = (int8_t)((v > 0.f) - (v < 0.f));
    }
    {
      float v0 = wadj[(size_t)co*CIN + 2*l];
      float v1 = wadj[(size_t)co*CIN + 2*l + 1];
      wbadj[co*64 + l] = f2bf(v0) | (f2bf(v1) << 16);
    }
  }

  int m = blockIdx.x*256 + threadIdx.x;     // m = n*S1 + hw
  int n = m / S1, hw = m % S1;
  size_t base = ((size_t)n*CIN + wdx*32)*S1 + hw;
  uint32_t p = 0, q = 0;
  uint32_t bv[16];
  #pragma unroll
  for (int j = 0; j < 32; ++j) {
    float v = x[base + (size_t)j*S1];
    p |= (uint32_t)(v > 0.f) << j;
    q |= (uint32_t)(v < 0.f) << j;
    uint32_t b = f2bf(v);
    if (j & 1) bv[j >> 1] |= b << 16; else bv[j >> 1] = b;
  }
  xbits[(size_t)m*8 + wdx    ] = p;
  xbits[(size_t)m*8 + 4 + wdx] = q;
  int h = hw / WW, w = hw % WW;
  if (((h | w) & 1) == 0) {
    int m2 = n*S2 + (h >> 1)*WO + (w >> 1);
    uint4* dst = (uint4*)(xg + (size_t)m2*64 + wdx*16);
    dst[0] = make_uint4(bv[0],  bv[1],  bv[2],  bv[3]);
    dst[1] = make_uint4(bv[4],  bv[5],  bv[6],  bv[7]);
    dst[2] = make_uint4(bv[8],  bv[9],  bv[10], bv[11]);
    dst[3] = make_uint4(bv[12], bv[13], bv[14], bv[15]);
  }
}

// ---------------- conv1: binary 1x1 XOR popcount + FUSED per-channel stats ----------------
// Rule-#20 compliant: NO runtime-indexed per-thread arrays. Results packed into
// wpk[8] dwords with static indices (registers), stored to global from scalars.
__global__ __launch_bounds__(256) void conv1_kernel(
    const uint32_t* __restrict__ xb, const uint32_t* __restrict__ wb,
    int8_t* __restrict__ out1, int* __restrict__ accum1) {
  int tid = threadIdx.x;
  int m = blockIdx.x*256 + tid;
  int n = m / S1, hw = m % S1;
  const uint32_t* xw = xb + (size_t)m*8;
  uint32_t p0 = xw[0], p1 = xw[1], p2 = xw[2], p3 = xw[3];
  uint32_t q0 = xw[4], q1 = xw[5], q2 = xw[6], q3 = xw[7];
  int co0 = blockIdx.y * 32;
  size_t obase = ((size_t)n*COUT)*S1 + hw;
  uint32_t wpk[8];
  bool nozero = (((p0|q0) & (p1|q1) & (p2|q2) & (p3|q3)) == 0xffffffffu);
  if (nozero) {
    #pragma unroll
    for (int jq = 0; jq < 8; ++jq) {
      uint32_t pk = 0;
      #pragma unroll
      for (int k = 0; k < 4; ++k) {
        int j = jq*4 + k;
        const uint32_t* w8 = wb + (size_t)(co0 + j)*8;
        int s = __popc(p0 ^ w8[0]) + __popc(p1 ^ w8[1])
              + __popc(p2 ^ w8[2]) + __popc(p3 ^ w8[3]);
        int acc = 128 - 2*s;
        if (acc > 127) acc = 127;
        out1[obase + (size_t)(co0 + j)*S1] = (int8_t)acc;
        pk |= (uint32_t)(uint8_t)acc << (8*k);
      }
      wpk[jq] = pk;
    }
  } else {
    #pragma unroll
    for (int jq = 0; jq < 8; ++jq) {
      uint32_t pk = 0;
      #pragma unroll
      for (int k = 0; k < 4; ++k) {
        int j = jq*4 + k;
        const uint32_t* w8 = wb + (size_t)(co0 + j)*8;
        uint32_t a0 = w8[0], a1 = w8[1], a2 = w8[2], a3 = w8[3];
        uint32_t b0 = w8[4], b1 = w8[5], b2 = w8[6], b3 = w8[7];
        int acc = __popc(p0&a0) + __popc(p1&a1) + __popc(p2&a2) + __popc(p3&a3)
                + __popc(q0&b0) + __popc(q1&b1) + __popc(q2&b2) + __popc(q3&b3)
                - __popc(p0&b0) - __popc(p1&b1) - __popc(p2&b2) - __popc(p3&b3)
                - __popc(q0&a0) - __popc(q1&a1) - __popc(q2&a2) - __popc(q3&a3);
        if (acc > 127) acc = 127;
        out1[obase + (size_t)(co0 + j)*S1] = (int8_t)acc;
        pk |= (uint32_t)(uint8_t)acc << (8*k);
      }
      wpk[jq] = pk;
    }
  }

  // fused stats. Write: row stride 36B = 9 dwords (odd -> conflict-light).
  __shared__ int8_t vals[256][36];
  #pragma unroll
  for (int k = 0; k < 8; ++k) *(uint32_t*)&vals[tid][4*k] = wpk[k];
  __syncthreads();
  int j = tid >> 3;     // channel 0..31 (8 per wave)
  int c = tid & 7;      // chunk 0..7
  int ps = 0, ns = 0, pq = 0, nq = 0;
  // interleaved row walk (rows c+8i): bank = (9c + j/4) mod 32 -> <=2-way (free)
  #pragma unroll
  for (int i = 0; i < 32; ++i) {
    int v = (int)vals[c + 8*i][j];
    if (v > 0) { ps += v; pq += v*v; } else { ns += v; nq += v*v; }
  }
  #pragma unroll
  for (int off = 4; off; off >>= 1) {
    ps += __shfl_xor(ps, off);
    ns += __shfl_xor(ns, off);
    pq += __shfl_xor(pq, off);
    nq += __shfl_xor(nq, off);
  }
  if (c == 0) {
    atomicAdd(&accum1[(co0 + j)*4 + 0], ps);
    atomicAdd(&accum1[(co0 + j)*4 + 1], ns);
    atomicAdd(&accum1[(co0 + j)*4 + 2], pq);
    atomicAdd(&accum1[(co0 + j)*4 + 3], nq);
  }
}

// ---------------- depthwise 3x3 s2 p1: LDS signs, inline thr1, fused stats2 ----------------
#define DW_SLABS 8
#define DW_RB    68
__global__ __launch_bounds__(256) void dw_kernel(
    const int8_t* __restrict__ out1, const int8_t* __restrict__ wdws,
    const int* __restrict__ acc1, const float* __restrict__ a1,
    const float* __restrict__ g1, const float* __restrict__ b1,
    int8_t* __restrict__ out2, int* __restrict__ accum2) {
  __shared__ int8_t sl[DW_SLABS][57][DW_RB];   // 30,464 B
  __shared__ int sTp[DW_SLABS], sTn[DW_SLABS], sAcc[DW_SLABS][4];
  int tid = threadIdx.x;
  int nc0 = blockIdx.x * DW_SLABS;
  int co0 = nc0 & (COUT-1);                    // 256 % 8 == 0: no wrap within block

  int* slw = (int*)&sl[0][0][0];
  #pragma unroll
  for (int i = tid; i < DW_SLABS*57*DW_RB/4; i += 256) slw[i] = 0;
  if (tid < DW_SLABS) { sTp[tid] = 128; sTn[tid] = -129; }
  if (tid < DW_SLABS*4) sAcc[tid >> 2][tid & 3] = 0;
  __syncthreads();

  // inline thresholds (32 threads per slab, 8 candidate v each)
  {
    int slab = tid >> 5;
    int co = co0 + slab;
    float av = a1[co], sc, sh;
    bn_finalize(acc1 + co*4, av, g1[co], b1[co], 1.f/NS1, sc, sh);
    int tp = 128, tn = -129;
    int v0 = -128 + (tid & 31)*8;
    #pragma unroll
    for (int k = 0; k < 8; ++k) {
      int v = v0 + k;
      float f = (float)v;
      float pr = f > 0.f ? f : av*f;
      float tv = pr*sc + sh;
      if (tv > 0.f && v < tp) tp = v;
      if (tv < 0.f && v > tn) tn = v;
    }
    atomicMin(&sTp[slab], tp);
    atomicMax(&sTn[slab], tn);
  }
  __syncthreads();

  // stage signs
  for (int i = tid; i < DW_SLABS*784; i += 256) {
    int slab = i / 784;
    int d    = i - slab*784;
    int ih   = d / 14;
    int iwd  = d - ih*14;
    int Tp = sTp[slab], Tn = sTn[slab];
    uint32_t v4 = ((const uint32_t*)(out1 + (size_t)(nc0 + slab)*S1))[d];
    uint32_t s4 = 0;
    #pragma unroll
    for (int k = 0; k < 4; ++k) {
      int v = (int)(int8_t)(v4 >> (8*k));
      int s = (v >= Tp) - (v <= Tn);
      s4 |= (uint32_t)(s & 0xff) << (8*k);
    }
    *(uint32_t*)&sl[slab][ih + 1][4 + 4*iwd] = s4;
  }
  __syncthreads();

  // compute one output row per thread (slab, ho) + local stats
  int psum = 0, nsum = 0, psq = 0, nsq = 0;
  int slabD = tid / HO;
  if (tid < DW_SLABS*HO) {
    int ho   = tid - slabD*HO;
    int nc = nc0 + slabD;
    int co = co0 + slabD;
    int wv[9];
    #pragma unroll
    for (int k = 0; k < 9; ++k) wv[k] = wdws[co*9 + k];
    const uint32_t* r0 = (const uint32_t*)&sl[slabD][2*ho    ][4];
    const uint32_t* r1 = (const uint32_t*)&sl[slabD][2*ho + 1][4];
    const uint32_t* r2 = (const uint32_t*)&sl[slabD][2*ho + 2][4];
    uint32_t* o32 = (uint32_t*)(out2 + (size_t)nc*S2 + ho*WO);
    int c0 = 0, c1 = 0, c2 = 0;
    uint32_t obuf = 0;
    #pragma unroll
    for (int q = 0; q < 14; ++q) {
      uint32_t d0 = r0[q], d1 = r1[q], d2 = r2[q];
      int s00=(int)(int8_t)d0, s01=(int)(int8_t)(d0>>8), s02=(int)(int8_t)(d0>>16), s03=(int)(int8_t)(d0>>24);
      int s10=(int)(int8_t)d1, s11=(int)(int8_t)(d1>>8), s12=(int)(int8_t)(d1>>16), s13=(int)(int8_t)(d1>>24);
      int s20=(int)(int8_t)d2, s21=(int)(int8_t)(d2>>8), s22=(int)(int8_t)(d2>>16), s23=(int)(int8_t)(d2>>24);
      int a0 = c0*wv[0] + s00*wv[1] + s01*wv[2]
             + c1*wv[3] + s10*wv[4] + s11*wv[5]
             + c2*wv[6] + s20*wv[7] + s21*wv[8];
      int a1v = s01*wv[0] + s02*wv[1] + s03*wv[2]
              + s11*wv[3] + s12*wv[4] + s13*wv[5]
              + s21*wv[6] + s22*wv[7] + s23*wv[8];
      c0 = s03; c1 = s13; c2 = s23;
      if (a0 > 0) { psum += a0; psq += a0*a0; } else { nsum += a0; nsq += a0*a0; }
      if (a1v > 0) { psum += a1v; psq += a1v*a1v; } else { nsum += a1v; nsq += a1v*a1v; }
      if ((q & 1) == 0) {
        obuf = (uint32_t)(a0 & 0xff) | ((uint32_t)(a1v & 0xff) << 8);
      } else {
        obuf |= ((uint32_t)(a0 & 0xff) << 16) | ((uint32_t)(a1v & 0xff) << 24);
        o32[q >> 1] = obuf;
      }
    }
    atomicAdd(&sAcc[slabD][0], psum);
    atomicAdd(&sAcc[slabD][1], nsum);
    atomicAdd(&sAcc[slabD][2], psq);
    atomicAdd(&sAcc[slabD][3], nsq);
  }
  __syncthreads();

  if (tid < DW_SLABS*4) {
    int slab = tid >> 2, k = tid & 3;
    atomicAdd(&accum2[(co0 + slab)*4 + k], sAcc[slab][k]);
  }
}

// ---------------- pack sign(BN2(prelu(out2))): inline thr2 + thresholds ----------------
__global__ __launch_bounds__(256) void pack2_kernel(
    const int8_t* __restrict__ out2, const int* __restrict__ acc2,
    const float* __restrict__ a2, const float* __restrict__ g2,
    const float* __restrict__ b2, uint32_t* __restrict__ xb2) {
  __shared__ int sTp[32], sTn[32];
  int wdx = blockIdx.y;                   // 0..7
  if (threadIdx.x < 32) {
    int c = wdx*32 + threadIdx.x;
    float av = a2[c], sc, sh;
    bn_finalize(acc2 + c*4, av, g2[c], b2[c], 1.f/NS2, sc, sh);
    int tp = 10, tn = -10;
    for (int v = -9; v <= 9; ++v) {
      float f = (float)v;
      float pr = f > 0.f ? f : av*f;
      float tv = pr*sc + sh;
      if (tv > 0.f && v < tp) tp = v;
      if (tv < 0.f && v > tn) tn = v;
    }
    sTp[threadIdx.x] = tp; sTn[threadIdx.x] = tn;
  }
  __syncthreads();
  int m = blockIdx.x*256 + threadIdx.x;   // n*S2 + hw
  int n = m / S2, hw = m % S2;
  uint32_t p = 0, q = 0;
  #pragma unroll
  for (int j = 0; j < 32; ++j) {
    int c = wdx*32 + j;
    int v = out2[(size_t)(n*COUT + c)*S2 + hw];
    p |= (uint32_t)(v >= sTp[j]) << j;
    q |= (uint32_t)(v <= sTn[j]) << j;
  }
  xb2[(size_t)m*16 + wdx    ] = p;
  xb2[(size_t)m*16 + 8 + wdx] = q;
}

// ---------------- conv3: binary 1x1 XOR fast path + FUSED per-channel stats ----------------
// Rule-#20 compliant: packed wpk[16] dwords, static indices only.
__global__ __launch_bounds__(256) void conv3_kernel(
    const uint32_t* __restrict__ xb2, const uint32_t* __restrict__ wb3,
    int16_t* __restrict__ out3, int* __restrict__ accum3) {
  int tid = threadIdx.x;
  int m = blockIdx.x*256 + tid;   // NS2
  int n = m / S2, hw = m % S2;
  const uint32_t* xw = xb2 + (size_t)m*16;
  uint32_t P[8], Q[8];
  #pragma unroll
  for (int i = 0; i < 8; ++i) { P[i] = xw[i]; Q[i] = xw[8+i]; }
  int co0 = blockIdx.y * 32;
  size_t obase = ((size_t)n*COUT)*S2 + hw;
  uint32_t wpk[16];
  uint32_t allm = 0xffffffffu;
  #pragma unroll
  for (int i = 0; i < 8; ++i) allm &= (P[i] | Q[i]);
  if (allm == 0xffffffffu) {
    #pragma unroll
    for (int jp = 0; jp < 16; ++jp) {
      uint32_t pk = 0;
      #pragma unroll
      for (int k = 0; k < 2; ++k) {
        int j = jp*2 + k;
        const uint32_t* w = wb3 + (size_t)(co0 + j)*16;
        int s = 0;
        #pragma unroll
        for (int i = 0; i < 8; ++i) s += __popc(P[i] ^ w[i]);
        int acc = 256 - 2*s;
        out3[obase + (size_t)(co0 + j)*S2] = (int16_t)acc;
        pk |= (uint32_t)(uint16_t)acc << (16*k);
      }
      wpk[jp] = pk;
    }
  } else {
    #pragma unroll
    for (int jp = 0; jp < 16; ++jp) {
      uint32_t pk = 0;
      #pragma unroll
      for (int k = 0; k < 2; ++k) {
        int j = jp*2 + k;
        const uint32_t* w = wb3 + (size_t)(co0 + j)*16;
        int acc = 0;
        #pragma unroll
        for (int i = 0; i < 8; ++i) {
          uint32_t wp = w[i], wn = w[8+i];
          acc += __popc(P[i]&wp) + __popc(Q[i]&wn) - __popc(P[i]&wn) - __popc(Q[i]&wp);
        }
        out3[obase + (size_t)(co0 + j)*S2] = (int16_t)acc;
        pk |= (uint32_t)(uint16_t)acc << (16*k);
      }
      wpk[jp] = pk;
    }
  }

  // fused stats. Write: row stride 68B = 17 dwords (odd -> conflict-light).
  __shared__ int16_t vals[256][34];
  #pragma unroll
  for (int k = 0; k < 16; ++k) *(uint32_t*)&vals[tid][2*k] = wpk[k];
  __syncthreads();
  int j = tid >> 3;     // channel 0..31
  int c = tid & 7;      // chunk
  int ps = 0, ns = 0, pq = 0, nq = 0;
  // interleaved row walk (rows c+8i): bank = (17c + j/2) mod 32 -> <=4-way
  #pragma unroll
  for (int i = 0; i < 32; ++i) {
    int v = (int)vals[c + 8*i][j];
    if (v > 0) { ps += v; pq += v*v; } else { ns += v; nq += v*v; }
  }
  #pragma unroll
  for (int off = 4; off; off >>= 1) {
    ps += __shfl_xor(ps, off);
    ns += __shfl_xor(ns, off);
    pq += __shfl_xor(pq, off);
    nq += __shfl_xor(nq, off);
  }
  if (c == 0) {
    atomicAdd(&accum3[(co0 + j)*4 + 0], ps);
    atomicAdd(&accum3[(co0 + j)*4 + 1], ns);
    atomicAdd(&accum3[(co0 + j)*4 + 2], pq);
    atomicAdd(&accum3[(co0 + j)*4 + 3], nq);
  }
}

// ---------------- fused residual (bf16 MFMA, all 256 co per wave) + BN3 + add ----------------
// block 256 = 4 waves; wave: 16 m x 256 co; grid NS2/64. xg read exactly once.
__global__ __launch_bounds__(256) void resfinal_kernel(
    const uint16_t* __restrict__ xg, const uint16_t* __restrict__ wb,
    const int16_t* __restrict__ out3,
    const float* __restrict__ a3, const float* __restrict__ g3,
    const float* __restrict__ b3, const int* __restrict__ acc3,
    float* __restrict__ out) {
  int lane = threadIdx.x & 63;
  int wid  = threadIdx.x >> 6;
  int m0  = blockIdx.x*64 + wid*16;
  int r16 = lane & 15, hi = lane >> 4;
  int koff = hi * 8;

  const bf16x8* arow = (const bf16x8*)(xg + (size_t)(m0 + r16)*CIN + koff);
  bf16x8 af0 = arow[0], af1 = arow[4], af2 = arow[8], af3 = arow[12];

  f32x4 dd[16];
  #pragma unroll
  for (int t = 0; t < 16; ++t) {
    const bf16x8* brow = (const bf16x8*)(wb + (size_t)(t*16 + r16)*CIN + koff);
    f32x4 a = {0.f,0.f,0.f,0.f};
    a = __builtin_amdgcn_mfma_f32_16x16x32_bf16(af0, brow[0],  a, 0,0,0);
    a = __builtin_amdgcn_mfma_f32_16x16x32_bf16(af1, brow[4],  a, 0,0,0);
    a = __builtin_amdgcn_mfma_f32_16x16x32_bf16(af2, brow[8],  a, 0,0,0);
    a = __builtin_amdgcn_mfma_f32_16x16x32_bf16(af3, brow[12], a, 0,0,0);
    dd[t] = a;
  }

  int mrow = m0 + hi*4;
  int n  = mrow / S2;               // 16-m tiles never straddle n (784 % 16 == 0)
  int hw = mrow - n*S2;
  #pragma unroll
  for (int t = 0; t < 16; ++t) {
    int co = t*16 + r16;
    float av = a3[co], sc, sh;
    bn_finalize(acc3 + co*4, av, g3[co], b3[co], 1.f/NS2, sc, sh);
    size_t o = ((size_t)n*COUT + co)*S2 + hw;
    #pragma unroll
    for (int r = 0; r < 4; ++r) {
      float f = (float)out3[o + r];
      float pp = f > 0.f ? f : av*f;
      out[o + r] = pp*sc + sh + dd[t][r];
    }
  }
}

extern "C" void kernel_launch(void* const* d_in, const int* in_sizes, int n_in,
                              void* d_out, int out_size, void* d_ws, size_t ws_size,
                              hipStream_t stream) {
  (void)in_sizes; (void)n_in; (void)out_size; (void)ws_size;
  const float* x    = (const float*)d_in[0];
  const float* w1   = (const float*)d_in[1];
  const float* a1   = (const float*)d_in[2];
  const float* g1   = (const float*)d_in[3];
  const float* b1   = (const float*)d_in[4];
  const float* wdw  = (const float*)d_in[5];
  const float* a2   = (const float*)d_in[6];
  const float* g2   = (const float*)d_in[7];
  const float* b2   = (const float*)d_in[8];
  const float* w3   = (const float*)d_in[9];
  const float* a3   = (const float*)d_in[10];
  const float* g3   = (const float*)d_in[11];
  const float* b3   = (const float*)d_in[12];
  const float* wadj = (const float*)d_in[13];
  float* out = (float*)d_out;

  char* ws = (char*)d_ws;
  uint32_t* xbits = (uint32_t*)(ws + OFF_XBITS);
  uint32_t* wb1   = (uint32_t*)(ws + OFF_WB1);
  uint32_t* wb3   = (uint32_t*)(ws + OFF_WB3);
  int8_t*   wdws  = (int8_t*)  (ws + OFF_WDW);
  int*      acc1  = (int*)     (ws + OFF_ACC);
  int*      acc2  = acc1 + 256*4;
  int*      acc3  = acc2 + 256*4;
  uint32_t* wbadj = (uint32_t*)(ws + OFF_WBADJ);
  uint32_t* xg    = (uint32_t*)(ws + OFF_XG);
  int8_t*   out1  = (int8_t*)  (ws + OFF_OUT1);
  int8_t*   out2  = (int8_t*)  (ws + OFF_OUT2);
  uint32_t* xb2   = (uint32_t*)(ws + OFF_XB2);
  int16_t*  out3  = (int16_t*) (ws + OFF_OUT3);

  packx_kernel<<<dim3(NS1/256, 4), 256, 0, stream>>>(
      x, xbits, xg, w1, w3, wdw, wadj, wb1, wb3, wdws, wbadj, acc1);
  conv1_kernel<<<dim3(NS1/256, 8), 256, 0, stream>>>(xbits, wb1, out1, acc1);
  dw_kernel<<<NB*COUT/DW_SLABS, 256, 0, stream>>>(out1, wdws, acc1, a1, g1, b1, out2, acc2);
  pack2_kernel<<<dim3(NS2/256, 8), 256, 0, stream>>>(out2, acc2, a2, g2, b2, xb2);
  conv3_kernel<<<dim3(NS2/256, 8), 256, 0, stream>>>(xb2, wb3, out3, acc3);
  resfinal_kernel<<<NS2/64, 256, 0, stream>>>(
      (const uint16_t*)xg, (const uint16_t*)wbadj, out3, a3, g3, b3, acc3, out);
}

// Round 14
// 109.028 us; speedup vs baseline: 3.0349x; 1.4486x over previous
//
#include <hip/hip_runtime.h>
#include <stdint.h>

// ---- problem dims ----
#define NB   32
#define CIN  128
#define COUT 256
#define HH   56
#define WW   56
#define S1   (HH*WW)      // 3136
#define HO   28
#define WO   28
#define S2   (HO*WO)      // 784
#define NS1  (NB*S1)      // 100352
#define NS2  (NB*S2)      // 25088
#define TOT2 (NS2*COUT)   // 6422528
#define EPSV 1e-5f

// ---- workspace layout (bytes) ----
constexpr size_t OFF_XBITS = 0;                                 // NS1*8*4 = 3,211,264
constexpr size_t OFF_WB1   = OFF_XBITS + (size_t)NS1*8*4;       // 8 KB
constexpr size_t OFF_WB3   = OFF_WB1 + 256*8*4;                 // 16 KB
constexpr size_t OFF_WDW   = OFF_WB3 + 256*16*4;                // 4 KB
constexpr size_t OFF_ACC   = OFF_WDW + 4096;                    // 12 KB
constexpr size_t OFF_WBADJ = OFF_ACC + 3*256*4*sizeof(int);     // 256*128*2 = 65,536
constexpr size_t OFF_XG    = OFF_WBADJ + (size_t)COUT*CIN*2;    // NS2*128*2 = 6,422,528
constexpr size_t OFF_OUT1  = OFF_XG + (size_t)NS2*CIN*2;        // NS1*COUT i8 = 25,690,112
constexpr size_t OFF_OUT2  = OFF_OUT1 + (size_t)NS1*COUT;       // i8 6,422,528
constexpr size_t OFF_XB2   = OFF_OUT2 + (size_t)TOT2;           // NS2*16*4 = 1,605,632
constexpr size_t OFF_OUT3  = OFF_XB2 + (size_t)NS2*16*4;        // i16 12,845,056
// total ~56 MB

typedef __attribute__((ext_vector_type(8))) short bf16x8;
typedef __attribute__((ext_vector_type(4))) float f32x4;

__device__ __forceinline__ uint32_t f2bf(float v) {
  uint32_t u = __float_as_uint(v);
  return (u + 0x7fffu + ((u >> 16) & 1u)) >> 16;   // RNE bf16 bits
}

// finalize BN scale/shift from exact integer sums of prelu output
__device__ __forceinline__ void bn_finalize(const int* __restrict__ acc4,
                                            float a, float g, float b, float inv_ns,
                                            float& sc, float& sh) {
  float ps = (float)acc4[0];   // sum of v where v>0
  float ng = (float)acc4[1];   // sum of v where v<0
  float pq = (float)acc4[2];   // sum of v^2 where v>0
  float nq = (float)acc4[3];   // sum of v^2 where v<0
  float mean = (ps + a*ng) * inv_ns;
  float ex2  = (pq + a*a*nq) * inv_ns;
  float var  = ex2 - mean*mean;
  float rs   = rsqrtf(var + EPSV);
  sc = rs * g;
  sh = b - mean * sc;
}

// ---------------- pack x into bitplanes + bf16 stride-2 tile, fused weight pack ----------------
__global__ __launch_bounds__(256) void packx_kernel(
    const float* __restrict__ x, uint32_t* __restrict__ xbits,
    uint32_t* __restrict__ xg,
    const float* __restrict__ w1, const float* __restrict__ w3,
    const float* __restrict__ wdw, const float* __restrict__ wadj,
    uint32_t* __restrict__ wb1, uint32_t* __restrict__ wb3,
    int8_t* __restrict__ wdws, uint32_t* __restrict__ wbadj,
    int* __restrict__ accbase) {
  int wdx = blockIdx.y;                     // 0..3
  // fused weight pack + acc zero: wave 0 of blocks (bx<256, wdx==0)
  if (wdx == 0 && blockIdx.x < 256 && threadIdx.x < 64) {
    int co = blockIdx.x;
    int l  = threadIdx.x;
    if (l < 12) {
      int set = l >> 2, k = l & 3;
      accbase[set*1024 + co*4 + k] = 0;
    }
    for (int h = 0; h < 2; ++h) {
      float v = w1[(size_t)co*CIN + h*64 + l];
      unsigned long long bp = __ballot(v > 0.f);
      unsigned long long bn = __ballot(v < 0.f);
      if (l == 0) {
        wb1[co*8 + 2*h    ] = (uint32_t)bp;
        wb1[co*8 + 2*h + 1] = (uint32_t)(bp >> 32);
        wb1[co*8 + 4 + 2*h    ] = (uint32_t)bn;
        wb1[co*8 + 4 + 2*h + 1] = (uint32_t)(bn >> 32);
      }
    }
    for (int h = 0; h < 4; ++h) {
      float v = w3[(size_t)co*COUT + h*64 + l];
      unsigned long long bp = __ballot(v > 0.f);
      unsigned long long bn = __ballot(v < 0.f);
      if (l == 0) {
        wb3[co*16 + 2*h    ] = (uint32_t)bp;
        wb3[co*16 + 2*h + 1] = (uint32_t)(bp >> 32);
        wb3[co*16 + 8 + 2*h    ] = (uint32_t)bn;
        wb3[co*16 + 8 + 2*h + 1] = (uint32_t)(bn >> 32);
      }
    }
    if (l < 9) {
      float v = wdw[co*9 + l];
      wdws[co*9 + l] = (int8_t)((v > 0.f) - (v < 0.f));
    }
    {
      float v0 = wadj[(size_t)co*CIN + 2*l];
      float v1 = wadj[(size_t)co*CIN + 2*l + 1];
      wbadj[co*64 + l] = f2bf(v0) | (f2bf(v1) << 16);
    }
  }

  int m = blockIdx.x*256 + threadIdx.x;     // m = n*S1 + hw
  int n = m / S1, hw = m % S1;
  size_t base = ((size_t)n*CIN + wdx*32)*S1 + hw;
  uint32_t p = 0, q = 0;
  uint32_t bv[16];
  #pragma unroll
  for (int j = 0; j < 32; ++j) {
    float v = x[base + (size_t)j*S1];
    p |= (uint32_t)(v > 0.f) << j;
    q |= (uint32_t)(v < 0.f) << j;
    uint32_t b = f2bf(v);
    if (j & 1) bv[j >> 1] |= b << 16; else bv[j >> 1] = b;
  }
  xbits[(size_t)m*8 + wdx    ] = p;
  xbits[(size_t)m*8 + 4 + wdx] = q;
  int h = hw / WW, w = hw % WW;
  if (((h | w) & 1) == 0) {
    int m2 = n*S2 + (h >> 1)*WO + (w >> 1);
    uint4* dst = (uint4*)(xg + (size_t)m2*64 + wdx*16);
    dst[0] = make_uint4(bv[0],  bv[1],  bv[2],  bv[3]);
    dst[1] = make_uint4(bv[4],  bv[5],  bv[6],  bv[7]);
    dst[2] = make_uint4(bv[8],  bv[9],  bv[10], bv[11]);
    dst[3] = make_uint4(bv[12], bv[13], bv[14], bv[15]);
  }
}

// ---------------- conv1: 4 m x 8 co per thread, coalesced dword stores + fused stats ----------
// quad of m never straddles n (4 | S1). Weights wave-uniform (SGPR). Stats via
// slot-reduce: sl[256][33] ints (stride 33 -> <=2-way banks), 32 slots = 8co x 4stats.
__global__ __launch_bounds__(256) void conv1_kernel(
    const uint32_t* __restrict__ xb, const uint32_t* __restrict__ wb,
    int8_t* __restrict__ out1, int* __restrict__ accum1) {
  int tid = threadIdx.x;
  int qm = blockIdx.x*256 + tid;        // 0..25087
  int m0 = qm*4;
  int n  = m0 / S1;
  int hw0 = m0 - n*S1;                  // 4-aligned
  int co0 = blockIdx.y * 8;

  const uint4* xw = (const uint4*)(xb + (size_t)m0*8);
  uint4 xp0 = xw[0], xq0 = xw[1];       // pixel 0: p words, q words
  uint4 xp1 = xw[2], xq1 = xw[3];
  uint4 xp2 = xw[4], xq2 = xw[5];
  uint4 xp3 = xw[6], xq3 = xw[7];

  uint32_t nz = (xp0.x|xq0.x)&(xp0.y|xq0.y)&(xp0.z|xq0.z)&(xp0.w|xq0.w)
              & (xp1.x|xq1.x)&(xp1.y|xq1.y)&(xp1.z|xq1.z)&(xp1.w|xq1.w)
              & (xp2.x|xq2.x)&(xp2.y|xq2.y)&(xp2.z|xq2.z)&(xp2.w|xq2.w)
              & (xp3.x|xq3.x)&(xp3.y|xq3.y)&(xp3.z|xq3.z)&(xp3.w|xq3.w);

  uint32_t res[8];
  if (nz == 0xffffffffu) {
    #pragma unroll
    for (int j = 0; j < 8; ++j) {
      const uint32_t* w8 = wb + (size_t)(co0 + j)*8;
      uint32_t w0 = w8[0], w1 = w8[1], w2 = w8[2], w3 = w8[3];
      int a0 = 128 - 2*(__popc(xp0.x^w0)+__popc(xp0.y^w1)+__popc(xp0.z^w2)+__popc(xp0.w^w3));
      int a1 = 128 - 2*(__popc(xp1.x^w0)+__popc(xp1.y^w1)+__popc(xp1.z^w2)+__popc(xp1.w^w3));
      int a2 = 128 - 2*(__popc(xp2.x^w0)+__popc(xp2.y^w1)+__popc(xp2.z^w2)+__popc(xp2.w^w3));
      int a3 = 128 - 2*(__popc(xp3.x^w0)+__popc(xp3.y^w1)+__popc(xp3.z^w2)+__popc(xp3.w^w3));
      if (a0 > 127) a0 = 127;
      if (a1 > 127) a1 = 127;
      if (a2 > 127) a2 = 127;
      if (a3 > 127) a3 = 127;
      res[j] = (uint32_t)(uint8_t)a0 | ((uint32_t)(uint8_t)a1 << 8)
             | ((uint32_t)(uint8_t)a2 << 16) | ((uint32_t)(uint8_t)a3 << 24);
    }
  } else {
    #pragma unroll
    for (int j = 0; j < 8; ++j) {
      const uint32_t* w8 = wb + (size_t)(co0 + j)*8;
      uint32_t w0 = w8[0], w1 = w8[1], w2 = w8[2], w3 = w8[3];
      uint32_t v0 = w8[4], v1 = w8[5], v2 = w8[6], v3 = w8[7];
      int a0 = __popc(xp0.x&w0)+__popc(xp0.y&w1)+__popc(xp0.z&w2)+__popc(xp0.w&w3)
             + __popc(xq0.x&v0)+__popc(xq0.y&v1)+__popc(xq0.z&v2)+__popc(xq0.w&v3)
             - __popc(xp0.x&v0)-__popc(xp0.y&v1)-__popc(xp0.z&v2)-__popc(xp0.w&v3)
             - __popc(xq0.x&w0)-__popc(xq0.y&w1)-__popc(xq0.z&w2)-__popc(xq0.w&w3);
      int a1 = __popc(xp1.x&w0)+__popc(xp1.y&w1)+__popc(xp1.z&w2)+__popc(xp1.w&w3)
             + __popc(xq1.x&v0)+__popc(xq1.y&v1)+__popc(xq1.z&v2)+__popc(xq1.w&v3)
             - __popc(xp1.x&v0)-__popc(xp1.y&v1)-__popc(xp1.z&v2)-__popc(xp1.w&v3)
             - __popc(xq1.x&w0)-__popc(xq1.y&w1)-__popc(xq1.z&w2)-__popc(xq1.w&w3);
      int a2 = __popc(xp2.x&w0)+__popc(xp2.y&w1)+__popc(xp2.z&w2)+__popc(xp2.w&w3)
             + __popc(xq2.x&v0)+__popc(xq2.y&v1)+__popc(xq2.z&v2)+__popc(xq2.w&v3)
             - __popc(xp2.x&v0)-__popc(xp2.y&v1)-__popc(xp2.z&v2)-__popc(xp2.w&v3)
             - __popc(xq2.x&w0)-__popc(xq2.y&w1)-__popc(xq2.z&w2)-__popc(xq2.w&w3);
      int a3 = __popc(xp3.x&w0)+__popc(xp3.y&w1)+__popc(xp3.z&w2)+__popc(xp3.w&w3)
             + __popc(xq3.x&v0)+__popc(xq3.y&v1)+__popc(xq3.z&v2)+__popc(xq3.w&v3)
             - __popc(xp3.x&v0)-__popc(xp3.y&v1)-__popc(xp3.z&v2)-__popc(xp3.w&v3)
             - __popc(xq3.x&w0)-__popc(xq3.y&w1)-__popc(xq3.z&w2)-__popc(xq3.w&w3);
      if (a0 > 127) a0 = 127;
      if (a1 > 127) a1 = 127;
      if (a2 > 127) a2 = 127;
      if (a3 > 127) a3 = 127;
      res[j] = (uint32_t)(uint8_t)a0 | ((uint32_t)(uint8_t)a1 << 8)
             | ((uint32_t)(uint8_t)a2 << 16) | ((uint32_t)(uint8_t)a3 << 24);
    }
  }

  // in-thread stats -> slot LDS
  __shared__ int sl[256][33];   // 33,792 B; bank = (tid + slot) mod 32
  #pragma unroll
  for (int j = 0; j < 8; ++j) {
    int b0 = (int)(int8_t)(res[j]);
    int b1 = (int)(int8_t)(res[j] >> 8);
    int b2 = (int)(int8_t)(res[j] >> 16);
    int b3 = (int)(int8_t)(res[j] >> 24);
    int ps = 0, ns = 0, pq = 0, nq = 0;
    if (b0 > 0) { ps += b0; pq += b0*b0; } else { ns += b0; nq += b0*b0; }
    if (b1 > 0) { ps += b1; pq += b1*b1; } else { ns += b1; nq += b1*b1; }
    if (b2 > 0) { ps += b2; pq += b2*b2; } else { ns += b2; nq += b2*b2; }
    if (b3 > 0) { ps += b3; pq += b3*b3; } else { ns += b3; nq += b3*b3; }
    sl[tid][j*4+0] = ps; sl[tid][j*4+1] = ns;
    sl[tid][j*4+2] = pq; sl[tid][j*4+3] = nq;
  }
  __syncthreads();

  // coalesced global stores AFTER barrier (drain overlaps reduce + kernel end)
  #pragma unroll
  for (int j = 0; j < 8; ++j)
    *(uint32_t*)(out1 + (size_t)(n*COUT + co0 + j)*S1 + hw0) = res[j];

  // slot reduce: 8 groups x 32 rows each
  int s = tid & 31, g = tid >> 5;
  int part = 0;
  #pragma unroll
  for (int i = 0; i < 32; ++i) part += sl[g*32 + i][s];
  part += __shfl_xor(part, 32);
  __shared__ int sW[4][32];
  if ((tid & 63) < 32) sW[tid >> 6][s] = part;
  __syncthreads();
  if (tid < 32) {
    int tot = sW[0][tid] + sW[1][tid] + sW[2][tid] + sW[3][tid];
    atomicAdd(&accum1[co0*4 + tid], tot);
  }
}

// ---------------- depthwise 3x3 s2 p1: LDS signs, inline thr1, fused stats2 ----------------
#define DW_SLABS 8
#define DW_RB    68
__global__ __launch_bounds__(256) void dw_kernel(
    const int8_t* __restrict__ out1, const int8_t* __restrict__ wdws,
    const int* __restrict__ acc1, const float* __restrict__ a1,
    const float* __restrict__ g1, const float* __restrict__ b1,
    int8_t* __restrict__ out2, int* __restrict__ accum2) {
  __shared__ int8_t sl[DW_SLABS][57][DW_RB];   // 30,464 B
  __shared__ int sTp[DW_SLABS], sTn[DW_SLABS], sAcc[DW_SLABS][4];
  int tid = threadIdx.x;
  int nc0 = blockIdx.x * DW_SLABS;
  int co0 = nc0 & (COUT-1);                    // 256 % 8 == 0: no wrap within block

  int* slw = (int*)&sl[0][0][0];
  #pragma unroll
  for (int i = tid; i < DW_SLABS*57*DW_RB/4; i += 256) slw[i] = 0;
  if (tid < DW_SLABS) { sTp[tid] = 128; sTn[tid] = -129; }
  if (tid < DW_SLABS*4) sAcc[tid >> 2][tid & 3] = 0;
  __syncthreads();

  // inline thresholds (32 threads per slab, 8 candidate v each)
  {
    int slab = tid >> 5;
    int co = co0 + slab;
    float av = a1[co], sc, sh;
    bn_finalize(acc1 + co*4, av, g1[co], b1[co], 1.f/NS1, sc, sh);
    int tp = 128, tn = -129;
    int v0 = -128 + (tid & 31)*8;
    #pragma unroll
    for (int k = 0; k < 8; ++k) {
      int v = v0 + k;
      float f = (float)v;
      float pr = f > 0.f ? f : av*f;
      float tv = pr*sc + sh;
      if (tv > 0.f && v < tp) tp = v;
      if (tv < 0.f && v > tn) tn = v;
    }
    atomicMin(&sTp[slab], tp);
    atomicMax(&sTn[slab], tn);
  }
  __syncthreads();

  // stage signs
  for (int i = tid; i < DW_SLABS*784; i += 256) {
    int slab = i / 784;
    int d    = i - slab*784;
    int ih   = d / 14;
    int iwd  = d - ih*14;
    int Tp = sTp[slab], Tn = sTn[slab];
    uint32_t v4 = ((const uint32_t*)(out1 + (size_t)(nc0 + slab)*S1))[d];
    uint32_t s4 = 0;
    #pragma unroll
    for (int k = 0; k < 4; ++k) {
      int v = (int)(int8_t)(v4 >> (8*k));
      int s = (v >= Tp) - (v <= Tn);
      s4 |= (uint32_t)(s & 0xff) << (8*k);
    }
    *(uint32_t*)&sl[slab][ih + 1][4 + 4*iwd] = s4;
  }
  __syncthreads();

  // compute one output row per thread (slab, ho) + local stats
  int psum = 0, nsum = 0, psq = 0, nsq = 0;
  int slabD = tid / HO;
  if (tid < DW_SLABS*HO) {
    int ho   = tid - slabD*HO;
    int nc = nc0 + slabD;
    int co = co0 + slabD;
    int wv[9];
    #pragma unroll
    for (int k = 0; k < 9; ++k) wv[k] = wdws[co*9 + k];
    const uint32_t* r0 = (const uint32_t*)&sl[slabD][2*ho    ][4];
    const uint32_t* r1 = (const uint32_t*)&sl[slabD][2*ho + 1][4];
    const uint32_t* r2 = (const uint32_t*)&sl[slabD][2*ho + 2][4];
    uint32_t* o32 = (uint32_t*)(out2 + (size_t)nc*S2 + ho*WO);
    int c0 = 0, c1 = 0, c2 = 0;
    uint32_t obuf = 0;
    #pragma unroll
    for (int q = 0; q < 14; ++q) {
      uint32_t d0 = r0[q], d1 = r1[q], d2 = r2[q];
      int s00=(int)(int8_t)d0, s01=(int)(int8_t)(d0>>8), s02=(int)(int8_t)(d0>>16), s03=(int)(int8_t)(d0>>24);
      int s10=(int)(int8_t)d1, s11=(int)(int8_t)(d1>>8), s12=(int)(int8_t)(d1>>16), s13=(int)(int8_t)(d1>>24);
      int s20=(int)(int8_t)d2, s21=(int)(int8_t)(d2>>8), s22=(int)(int8_t)(d2>>16), s23=(int)(int8_t)(d2>>24);
      int a0 = c0*wv[0] + s00*wv[1] + s01*wv[2]
             + c1*wv[3] + s10*wv[4] + s11*wv[5]
             + c2*wv[6] + s20*wv[7] + s21*wv[8];
      int a1v = s01*wv[0] + s02*wv[1] + s03*wv[2]
              + s11*wv[3] + s12*wv[4] + s13*wv[5]
              + s21*wv[6] + s22*wv[7] + s23*wv[8];
      c0 = s03; c1 = s13; c2 = s23;
      if (a0 > 0) { psum += a0; psq += a0*a0; } else { nsum += a0; nsq += a0*a0; }
      if (a1v > 0) { psum += a1v; psq += a1v*a1v; } else { nsum += a1v; nsq += a1v*a1v; }
      if ((q & 1) == 0) {
        obuf = (uint32_t)(a0 & 0xff) | ((uint32_t)(a1v & 0xff) << 8);
      } else {
        obuf |= ((uint32_t)(a0 & 0xff) << 16) | ((uint32_t)(a1v & 0xff) << 24);
        o32[q >> 1] = obuf;
      }
    }
    atomicAdd(&sAcc[slabD][0], psum);
    atomicAdd(&sAcc[slabD][1], nsum);
    atomicAdd(&sAcc[slabD][2], psq);
    atomicAdd(&sAcc[slabD][3], nsq);
  }
  __syncthreads();

  if (tid < DW_SLABS*4) {
    int slab = tid >> 2, k = tid & 3;
    atomicAdd(&accum2[(co0 + slab)*4 + k], sAcc[slab][k]);
  }
}

// ---------------- pack sign(BN2(prelu(out2))): inline thr2 + thresholds ----------------
__global__ __launch_bounds__(256) void pack2_kernel(
    const int8_t* __restrict__ out2, const int* __restrict__ acc2,
    const float* __restrict__ a2, const float* __restrict__ g2,
    const float* __restrict__ b2, uint32_t* __restrict__ xb2) {
  __shared__ int sTp[32], sTn[32];
  int wdx = blockIdx.y;                   // 0..7
  if (threadIdx.x < 32) {
    int c = wdx*32 + threadIdx.x;
    float av = a2[c], sc, sh;
    bn_finalize(acc2 + c*4, av, g2[c], b2[c], 1.f/NS2, sc, sh);
    int tp = 10, tn = -10;
    for (int v = -9; v <= 9; ++v) {
      float f = (float)v;
      float pr = f > 0.f ? f : av*f;
      float tv = pr*sc + sh;
      if (tv > 0.f && v < tp) tp = v;
      if (tv < 0.f && v > tn) tn = v;
    }
    sTp[threadIdx.x] = tp; sTn[threadIdx.x] = tn;
  }
  __syncthreads();
  int m = blockIdx.x*256 + threadIdx.x;   // n*S2 + hw
  int n = m / S2, hw = m % S2;
  uint32_t p = 0, q = 0;
  #pragma unroll
  for (int j = 0; j < 32; ++j) {
    int c = wdx*32 + j;
    int v = out2[(size_t)(n*COUT + c)*S2 + hw];
    p |= (uint32_t)(v >= sTp[j]) << j;
    q |= (uint32_t)(v <= sTn[j]) << j;
  }
  xb2[(size_t)m*16 + wdx    ] = p;
  xb2[(size_t)m*16 + 8 + wdx] = q;
}

// ---------------- conv3: 2 m x 8 co per thread, coalesced dword stores + fused stats ----------
__global__ __launch_bounds__(256) void conv3_kernel(
    const uint32_t* __restrict__ xb2, const uint32_t* __restrict__ wb3,
    int16_t* __restrict__ out3, int* __restrict__ accum3) {
  int tid = threadIdx.x;
  int qm = blockIdx.x*256 + tid;        // 0..12543
  int m0 = qm*2;
  int n  = m0 / S2;
  int hw0 = m0 - n*S2;                  // even
  int co0 = blockIdx.y * 8;

  const uint4* xw = (const uint4*)(xb2 + (size_t)m0*16);
  uint4 P0a = xw[0], P0b = xw[1], Q0a = xw[2], Q0b = xw[3];
  uint4 P1a = xw[4], P1b = xw[5], Q1a = xw[6], Q1b = xw[7];

  uint32_t nz = (P0a.x|Q0a.x)&(P0a.y|Q0a.y)&(P0a.z|Q0a.z)&(P0a.w|Q0a.w)
              & (P0b.x|Q0b.x)&(P0b.y|Q0b.y)&(P0b.z|Q0b.z)&(P0b.w|Q0b.w)
              & (P1a.x|Q1a.x)&(P1a.y|Q1a.y)&(P1a.z|Q1a.z)&(P1a.w|Q1a.w)
              & (P1b.x|Q1b.x)&(P1b.y|Q1b.y)&(P1b.z|Q1b.z)&(P1b.w|Q1b.w);

  uint32_t res[8];
  if (nz == 0xffffffffu) {
    #pragma unroll
    for (int j = 0; j < 8; ++j) {
      const uint32_t* w = wb3 + (size_t)(co0 + j)*16;
      int s0 = __popc(P0a.x^w[0])+__popc(P0a.y^w[1])+__popc(P0a.z^w[2])+__popc(P0a.w^w[3])
             + __popc(P0b.x^w[4])+__popc(P0b.y^w[5])+__popc(P0b.z^w[6])+__popc(P0b.w^w[7]);
      int s1 = __popc(P1a.x^w[0])+__popc(P1a.y^w[1])+__popc(P1a.z^w[2])+__popc(P1a.w^w[3])
             + __popc(P1b.x^w[4])+__popc(P1b.y^w[5])+__popc(P1b.z^w[6])+__popc(P1b.w^w[7]);
      int a0 = 256 - 2*s0, a1 = 256 - 2*s1;
      res[j] = (uint32_t)(uint16_t)(int16_t)a0 | ((uint32_t)(uint16_t)(int16_t)a1 << 16);
    }
  } else {
    #pragma unroll
    for (int j = 0; j < 8; ++j) {
      const uint32_t* w = wb3 + (size_t)(co0 + j)*16;
      int a0 = __popc(P0a.x&w[0])+__popc(P0a.y&w[1])+__popc(P0a.z&w[2])+__popc(P0a.w&w[3])
             + __popc(P0b.x&w[4])+__popc(P0b.y&w[5])+__popc(P0b.z&w[6])+__popc(P0b.w&w[7])
             + __popc(Q0a.x&w[8])+__popc(Q0a.y&w[9])+__popc(Q0a.z&w[10])+__popc(Q0a.w&w[11])
             + __popc(Q0b.x&w[12])+__popc(Q0b.y&w[13])+__popc(Q0b.z&w[14])+__popc(Q0b.w&w[15])
             - __popc(P0a.x&w[8])-__popc(P0a.y&w[9])-__popc(P0a.z&w[10])-__popc(P0a.w&w[11])
             - __popc(P0b.x&w[12])-__popc(P0b.y&w[13])-__popc(P0b.z&w[14])-__popc(P0b.w&w[15])
             - __popc(Q0a.x&w[0])-__popc(Q0a.y&w[1])-__popc(Q0a.z&w[2])-__popc(Q0a.w&w[3])
             - __popc(Q0b.x&w[4])-__popc(Q0b.y&w[5])-__popc(Q0b.z&w[6])-__popc(Q0b.w&w[7]);
      int a1 = __popc(P1a.x&w[0])+__popc(P1a.y&w[1])+__popc(P1a.z&w[2])+__popc(P1a.w&w[3])
             + __popc(P1b.x&w[4])+__popc(P1b.y&w[5])+__popc(P1b.z&w[6])+__popc(P1b.w&w[7])
             + __popc(Q1a.x&w[8])+__popc(Q1a.y&w[9])+__popc(Q1a.z&w[10])+__popc(Q1a.w&w[11])
             + __popc(Q1b.x&w[12])+__popc(Q1b.y&w[13])+__popc(Q1b.z&w[14])+__popc(Q1b.w&w[15])
             - __popc(P1a.x&w[8])-__popc(P1a.y&w[9])-__popc(P1a.z&w[10])-__popc(P1a.w&w[11])
             - __popc(P1b.x&w[12])-__popc(P1b.y&w[13])-__popc(P1b.z&w[14])-__popc(P1b.w&w[15])
             - __popc(Q1a.x&w[0])-__popc(Q1a.y&w[1])-__popc(Q1a.z&w[2])-__popc(Q1a.w&w[3])
             - __popc(Q1b.x&w[4])-__popc(Q1b.y&w[5])-__popc(Q1b.z&w[6])-__popc(Q1b.w&w[7]);
      res[j] = (uint32_t)(uint16_t)(int16_t)a0 | ((uint32_t)(uint16_t)(int16_t)a1 << 16);
    }
  }

  __shared__ int sl[256][33];
  #pragma unroll
  for (int j = 0; j < 8; ++j) {
    int b0 = (int)(int16_t)(res[j] & 0xffff);
    int b1 = (int)(int16_t)(res[j] >> 16);
    int ps = 0, ns = 0, pq = 0, nq = 0;
    if (b0 > 0) { ps += b0; pq += b0*b0; } else { ns += b0; nq += b0*b0; }
    if (b1 > 0) { ps += b1; pq += b1*b1; } else { ns += b1; nq += b1*b1; }
    sl[tid][j*4+0] = ps; sl[tid][j*4+1] = ns;
    sl[tid][j*4+2] = pq; sl[tid][j*4+3] = nq;
  }
  __syncthreads();

  #pragma unroll
  for (int j = 0; j < 8; ++j)
    *(uint32_t*)(out3 + (size_t)(n*COUT + co0 + j)*S2 + hw0) = res[j];

  int s = tid & 31, g = tid >> 5;
  int part = 0;
  #pragma unroll
  for (int i = 0; i < 32; ++i) part += sl[g*32 + i][s];
  part += __shfl_xor(part, 32);
  __shared__ int sW[4][32];
  if ((tid & 63) < 32) sW[tid >> 6][s] = part;
  __syncthreads();
  if (tid < 32) {
    int tot = sW[0][tid] + sW[1][tid] + sW[2][tid] + sW[3][tid];
    atomicAdd(&accum3[co0*4 + tid], tot);
  }
}

// ---------------- fused residual (bf16 MFMA, all 256 co per wave) + BN3 + add ----------------
// block 256 = 4 waves; wave: 16 m x 256 co; grid NS2/64. xg read exactly once.
__global__ __launch_bounds__(256) void resfinal_kernel(
    const uint16_t* __restrict__ xg, const uint16_t* __restrict__ wb,
    const int16_t* __restrict__ out3,
    const float* __restrict__ a3, const float* __restrict__ g3,
    const float* __restrict__ b3, const int* __restrict__ acc3,
    float* __restrict__ out) {
  int lane = threadIdx.x & 63;
  int wid  = threadIdx.x >> 6;
  int m0  = blockIdx.x*64 + wid*16;
  int r16 = lane & 15, hi = lane >> 4;
  int koff = hi * 8;

  const bf16x8* arow = (const bf16x8*)(xg + (size_t)(m0 + r16)*CIN + koff);
  bf16x8 af0 = arow[0], af1 = arow[4], af2 = arow[8], af3 = arow[12];

  f32x4 dd[16];
  #pragma unroll
  for (int t = 0; t < 16; ++t) {
    const bf16x8* brow = (const bf16x8*)(wb + (size_t)(t*16 + r16)*CIN + koff);
    f32x4 a = {0.f,0.f,0.f,0.f};
    a = __builtin_amdgcn_mfma_f32_16x16x32_bf16(af0, brow[0],  a, 0,0,0);
    a = __builtin_amdgcn_mfma_f32_16x16x32_bf16(af1, brow[4],  a, 0,0,0);
    a = __builtin_amdgcn_mfma_f32_16x16x32_bf16(af2, brow[8],  a, 0,0,0);
    a = __builtin_amdgcn_mfma_f32_16x16x32_bf16(af3, brow[12], a, 0,0,0);
    dd[t] = a;
  }

  int mrow = m0 + hi*4;
  int n  = mrow / S2;               // 16-m tiles never straddle n (784 % 16 == 0)
  int hw = mrow - n*S2;
  #pragma unroll
  for (int t = 0; t < 16; ++t) {
    int co = t*16 + r16;
    float av = a3[co], sc, sh;
    bn_finalize(acc3 + co*4, av, g3[co], b3[co], 1.f/NS2, sc, sh);
    size_t o = ((size_t)n*COUT + co)*S2 + hw;
    #pragma unroll
    for (int r = 0; r < 4; ++r) {
      float f = (float)out3[o + r];
      float pp = f > 0.f ? f : av*f;
      out[o + r] = pp*sc + sh + dd[t][r];
    }
  }
}

extern "C" void kernel_launch(void* const* d_in, const int* in_sizes, int n_in,
                              void* d_out, int out_size, void* d_ws, size_t ws_size,
                              hipStream_t stream) {
  (void)in_sizes; (void)n_in; (void)out_size; (void)ws_size;
  const float* x    = (const float*)d_in[0];
  const float* w1   = (const float*)d_in[1];
  const float* a1   = (const float*)d_in[2];
  const float* g1   = (const float*)d_in[3];
  const float* b1   = (const float*)d_in[4];
  const float* wdw  = (const float*)d_in[5];
  const float* a2   = (const float*)d_in[6];
  const float* g2   = (const float*)d_in[7];
  const float* b2   = (const float*)d_in[8];
  const float* w3   = (const float*)d_in[9];
  const float* a3   = (const float*)d_in[10];
  const float* g3   = (const float*)d_in[11];
  const float* b3   = (const float*)d_in[12];
  const float* wadj = (const float*)d_in[13];
  float* out = (float*)d_out;

  char* ws = (char*)d_ws;
  uint32_t* xbits = (uint32_t*)(ws + OFF_XBITS);
  uint32_t* wb1   = (uint32_t*)(ws + OFF_WB1);
  uint32_t* wb3   = (uint32_t*)(ws + OFF_WB3);
  int8_t*   wdws  = (int8_t*)  (ws + OFF_WDW);
  int*      acc1  = (int*)     (ws + OFF_ACC);
  int*      acc2  = acc1 + 256*4;
  int*      acc3  = acc2 + 256*4;
  uint32_t* wbadj = (uint32_t*)(ws + OFF_WBADJ);
  uint32_t* xg    = (uint32_t*)(ws + OFF_XG);
  int8_t*   out1  = (int8_t*)  (ws + OFF_OUT1);
  int8_t*   out2  = (int8_t*)  (ws + OFF_OUT2);
  uint32_t* xb2   = (uint32_t*)(ws + OFF_XB2);
  int16_t*  out3  = (int16_t*) (ws + OFF_OUT3);

  packx_kernel<<<dim3(NS1/256, 4), 256, 0, stream>>>(
      x, xbits, xg, w1, w3, wdw, wadj, wb1, wb3, wdws, wbadj, acc1);
  conv1_kernel<<<dim3(NS1/1024, 32), 256, 0, stream>>>(xbits, wb1, out1, acc1);
  dw_kernel<<<NB*COUT/DW_SLABS, 256, 0, stream>>>(out1, wdws, acc1, a1, g1, b1, out2, acc2);
  pack2_kernel<<<dim3(NS2/256, 8), 256, 0, stream>>>(out2, acc2, a2, g2, b2, xb2);
  conv3_kernel<<<dim3(NS2/512, 32), 256, 0, stream>>>(xb2, wb3, out3, acc3);
  resfinal_kernel<<<NS2/64, 256, 0, stream>>>(
      (const uint16_t*)xg, (const uint16_t*)wbadj, out3, a3, g3, b3, acc3, out);
}